// Round 7
// baseline (166.429 us; speedup 1.0000x reference)
//
#include <hip/hip_runtime.h>
#include <math.h>

// B=64, A=64, MULS=((64,0),(32,1),(16,2)) -> DIM_IN=240, NB=32, H=128, MOUT=112
#define H_ 128
#define NB_ 32

#define INV_STEP 3.1f
#define HALF_PI 1.57079632679489662f
#define INV_SQRT_NB 0.17677669529663689f
#define INV_SQRT_H 0.08838834764831845f
#define NORM0 0.125f
#define NORM1 0.10206207261596575f
#define NORM2 0.11180339887498948f
#define S3 1.7320508075688772f
#define S5 2.23606797749979f
#define S15 3.872983346207417f
#define LN2 0.6931471805599453f

typedef __attribute__((ext_vector_type(8))) _Float16 half8;
typedef __attribute__((ext_vector_type(4))) float f32x4;

__device__ __forceinline__ float ssp_f(float x) {
    float t = 5.0f * x;
    float s = fmaxf(t, 0.0f) + __logf(1.0f + __expf(-fabsf(t)));
    return (s - LN2) * 0.2f;
}
__device__ __forceinline__ float sp_f(float x) {
    float t = 5.0f * x;
    float s = fmaxf(t, 0.0f) + __logf(1.0f + __expf(-fabsf(t)));
    return s * 0.2f;
}

// ---------------------------------------------------------------------------
// Single fused kernel. Grid (8, 64): blockIdx.x = bg (8 b's), y = z.
// 256 threads, 2 blocks/CU (LDS ~72 KB, VGPR <=256 via launch_bounds(256,2)).
//
// Startup: geom/rep/W1(fp32, padded rows)/W2(->fp16 transposed) into LDS;
//          gather all 32 W2 MFMA-B-fragments into VGPRs (persist whole kernel);
//          compute V[8b] from rep/W3, emit fp16 B-frags into LDS (reusing the
//          W2-staging region).
// Main (8 passes, 1 b each): layer1 in fp16 A-frag regs (W1 from LDS) ->
//          fp16 MFMA layer2 (B from VGPRs) -> ssp -> fp16 LDS transpose
//          (stride 136 halfs, 16B-aligned b128 reads) -> fp16 MFMA combine vs
//          V frags -> G-weight -> 16-lane shuffle reduce.
// Output:  partial[z][bg][a] via agent-scope stores; completion counter per z
//          (ws poisoned 0xAA -> initial 0xAAAAAAAA); 8th block reduces and
//          writes out = sp(sum/sqrt(n_atoms))*mask.
// ---------------------------------------------------------------------------
__global__ __launch_bounds__(256, 2)
void fused1(const float* __restrict__ rep, const float* __restrict__ geom,
            const float* __restrict__ mask, const float* __restrict__ W1,
            const float* __restrict__ W2, const float* __restrict__ W3,
            float* __restrict__ partial, unsigned* __restrict__ counter,
            float* __restrict__ out) {
    const int bg = blockIdx.x;           // b in [8bg, 8bg+8)
    const int z  = blockIdx.y;
    const int tid = threadIdx.x;
    const int wv = tid >> 6, lane = tid & 63;
    const int m = lane & 15, quad = lane >> 4;

    // region X: W2^T fp16 [n=128][stride 136] (34816 B), later sVf (32768 B)
    __shared__ __align__(16) char sX[34816];
    _Float16* sW2t = reinterpret_cast<_Float16*>(sX);
    _Float16* sVf  = reinterpret_cast<_Float16*>(sX);
    // region H: H2 transpose bufs fp16 [wave][16][136] (17408 B); sRep alias
    __shared__ __align__(16) char sH[17408];
    _Float16* sH2 = reinterpret_cast<_Float16*>(sH);
    float* sRep = reinterpret_cast<float*>(sH);          // 1920 floats
    __shared__ __align__(16) float sW1[32 * 132];        // 16896 B (padded rows)
    __shared__ float sPosA[192];
    __shared__ float sPosB[24];
    __shared__ __align__(16) float sYw[4][16][8];        // 2048 B
    __shared__ unsigned sLastFlag;

    // ---- stage geom, rep, W1, W2 ----
    if (tid < 192) sPosA[tid] = geom[z * 192 + tid];
    else if (tid < 216) sPosB[tid - 192] = geom[((size_t)z * 64 + bg * 8) * 3 + (tid - 192)];
    {
        const float4* src = reinterpret_cast<const float4*>(rep + ((size_t)z * 64 + bg * 8) * 240);
        float4* dst = reinterpret_cast<float4*>(sRep);
        for (int i = tid; i < 480; i += 256) dst[i] = src[i];
    }
    for (int g = tid; g < 1024; g += 256) {              // W1: 32x128 -> stride 132
        float4 v = reinterpret_cast<const float4*>(W1)[g];
        int row = g >> 5, c = (g & 31) * 4;
        *reinterpret_cast<float4*>(&sW1[row * 132 + c]) = v;
    }
    for (int g = tid; g < 4096; g += 256) {              // W2 -> fp16 transposed
        float4 v = reinterpret_cast<const float4*>(W2)[g];
        int k = g >> 5, n0 = (g & 31) * 4;
        sW2t[(n0 + 0) * 136 + k] = (_Float16)v.x;
        sW2t[(n0 + 1) * 136 + k] = (_Float16)v.y;
        sW2t[(n0 + 2) * 136 + k] = (_Float16)v.z;
        sW2t[(n0 + 3) * 136 + k] = (_Float16)v.w;
    }
    __syncthreads();

    // ---- gather W2 B-frags into VGPRs (persist) ----
    half8 w2r[4][8];
    #pragma unroll
    for (int kt = 0; kt < 4; ++kt)
        #pragma unroll
        for (int nt = 0; nt < 8; ++nt)
            w2r[kt][nt] = *reinterpret_cast<const half8*>(
                &sW2t[(nt * 16 + m) * 136 + kt * 32 + quad * 8]);
    __syncthreads();   // everyone gathered; region X reusable

    // ---- V compute: 1024 (b,h) slots; emit fp16 B-frags into sVf ----
    #pragma unroll
    for (int i = 0; i < 4; ++i) {
        const int s = tid + i * 256;
        const int b = s >> 7, h = s & 127;
        const float* w3r = W3 + (size_t)h * 112;
        const float* rr = sRep + b * 240;
        float a0 = 0.f, a1 = 0.f, a2 = 0.f, a3 = 0.f, a4 = 0.f,
              a5 = 0.f, a6 = 0.f, a7 = 0.f, a8 = 0.f;
        #pragma unroll 4
        for (int m4 = 0; m4 < 16; ++m4) {            // l=0
            float4 w = *reinterpret_cast<const float4*>(w3r + m4 * 4);
            const float* wp = reinterpret_cast<const float*>(&w);
            #pragma unroll
            for (int c = 0; c < 4; ++c) a0 = fmaf(wp[c], rr[m4 * 4 + c], a0);
        }
        #pragma unroll 2
        for (int u4 = 0; u4 < 8; ++u4) {             // l=1
            float4 w = *reinterpret_cast<const float4*>(w3r + 64 + u4 * 4);
            const float* wp = reinterpret_cast<const float*>(&w);
            #pragma unroll
            for (int c = 0; c < 4; ++c) {
                int u = u4 * 4 + c;
                a1 = fmaf(wp[c], rr[64 + 3 * u + 0], a1);
                a2 = fmaf(wp[c], rr[64 + 3 * u + 1], a2);
                a3 = fmaf(wp[c], rr[64 + 3 * u + 2], a3);
            }
        }
        #pragma unroll 2
        for (int u4 = 0; u4 < 4; ++u4) {             // l=2
            float4 w = *reinterpret_cast<const float4*>(w3r + 96 + u4 * 4);
            const float* wp = reinterpret_cast<const float*>(&w);
            #pragma unroll
            for (int c = 0; c < 4; ++c) {
                int u = u4 * 4 + c;
                a4 = fmaf(wp[c], rr[160 + 5 * u + 0], a4);
                a5 = fmaf(wp[c], rr[160 + 5 * u + 1], a5);
                a6 = fmaf(wp[c], rr[160 + 5 * u + 2], a6);
                a7 = fmaf(wp[c], rr[160 + 5 * u + 3], a7);
                a8 = fmaf(wp[c], rr[160 + 5 * u + 4], a8);
            }
        }
        const float n0 = NORM0 * INV_SQRT_H, n1 = NORM1 * INV_SQRT_H, n2 = NORM2 * INV_SQRT_H;
        float vals[9];
        vals[0] = a0 * n0;
        vals[1] = a1 * n1; vals[2] = a2 * n1; vals[3] = a3 * n1;
        vals[4] = a4 * n2; vals[5] = a5 * n2; vals[6] = a6 * n2;
        vals[7] = a7 * n2; vals[8] = a8 * n2;
        const int kt = h >> 5, qd = (h >> 3) & 3, j = h & 7;
        _Float16* base = sVf + (b * 4 + kt) * 512 + qd * 128 + j;
        #pragma unroll
        for (int n = 0; n < 16; ++n)
            base[n * 8] = (n < 9) ? (_Float16)vals[n] : (_Float16)0.0f;
    }
    __syncthreads();   // sVf ready; sRep dead -> sH2 usable

    // ---- main loop: 8 passes, 1 b each ----
    const float ax = sPosA[m * 3 + 0];   // wave's a-tile is the SAME 16 a's? no:
    // a-local for this wave = wv*16 + m
    const int aLoc = wv * 16 + m;
    const float axw = sPosA[aLoc * 3 + 0];
    const float ayw = sPosA[aLoc * 3 + 1];
    const float azw = sPosA[aLoc * 3 + 2];
    (void)ax;
    _Float16* myH2 = sH2 + wv * 16 * 136;
    float outAcc[4] = {0.f, 0.f, 0.f, 0.f};

    for (int bl = 0; bl < 8; ++bl) {
        // pair geometry (per lane; quads redundant but cheap)
        const float bx = sPosB[bl * 3 + 0];
        const float by = sPosB[bl * 3 + 1];
        const float bz = sPosB[bl * 3 + 2];
        const float dx = axw - bx, dy = ayw - by, dz = azw - bz;
        const float r2 = dx * dx + dy * dy + dz * dz;
        const float r = sqrtf(fmaxf(r2, 1e-12f));
        const float nzf = (r2 > 1e-10f) ? 1.0f : 0.0f;
        const float ir = 1.0f / r;
        const float x = dx * ir, y = dy * ir, zz = dz * ir;
        if (quad == 0) {
            float4 g0, g1;
            g0.x = S3 * x * nzf; g0.y = S3 * y * nzf; g0.z = S3 * zz * nzf;
            g0.w = S15 * x * y * nzf;
            g1.x = S15 * y * zz * nzf;
            g1.y = 0.5f * S5 * (3.0f * zz * zz - 1.0f) * nzf;
            g1.z = S15 * x * zz * nzf;
            g1.w = 0.5f * S15 * (x * x - y * y) * nzf;
            *reinterpret_cast<float4*>(&sYw[wv][m][0]) = g0;
            *reinterpret_cast<float4*>(&sYw[wv][m][4]) = g1;
        }
        const float u = r * INV_STEP;
        int i0 = (int)floorf(u);
        const float d0 = u - (float)i0;
        float c0 = (i0 >= 0 && i0 < NB_) ? __cosf(HALF_PI * d0) : 0.f;
        const int i1 = i0 + 1;
        const float d1 = d0 - 1.0f;
        float c1 = (i1 >= 0 && i1 < NB_ && d1 > -1.0f) ? __cosf(HALF_PI * d1) : 0.f;
        const int i0c = min(max(i0, 0), NB_ - 1);
        const int i1c = min(max(i1, 0), NB_ - 1);
        const float c0v = c0 * INV_SQRT_NB;
        const float c1v = c1 * INV_SQRT_NB;
        const float* w1r0 = &sW1[i0c * 132];
        const float* w1r1 = &sW1[i1c * 132];

        f32x4 acc[8];
        #pragma unroll
        for (int nt = 0; nt < 8; ++nt) {
            acc[nt][0] = 0.f; acc[nt][1] = 0.f; acc[nt][2] = 0.f; acc[nt][3] = 0.f;
        }

        // layer1 (fp16 A-frag regs from LDS W1) + layer2 MFMA (B from VGPRs)
        #pragma unroll
        for (int kt = 0; kt < 4; ++kt) {
            const int koff = kt * 32 + quad * 8;
            float4 wa0 = *reinterpret_cast<const float4*>(w1r0 + koff);
            float4 wa1 = *reinterpret_cast<const float4*>(w1r0 + koff + 4);
            float4 wb0 = *reinterpret_cast<const float4*>(w1r1 + koff);
            float4 wb1 = *reinterpret_cast<const float4*>(w1r1 + koff + 4);
            const float* a0p = reinterpret_cast<const float*>(&wa0);
            const float* a1p = reinterpret_cast<const float*>(&wa1);
            const float* b0p = reinterpret_cast<const float*>(&wb0);
            const float* b1p = reinterpret_cast<const float*>(&wb1);
            half8 ah;
            #pragma unroll
            for (int j = 0; j < 8; ++j) {
                float w0 = (j < 4) ? a0p[j] : a1p[j - 4];
                float w1v = (j < 4) ? b0p[j] : b1p[j - 4];
                ah[j] = (_Float16)ssp_f(fmaf(c0v, w0, c1v * w1v));
            }
            #pragma unroll
            for (int nt = 0; nt < 8; ++nt)
                acc[nt] = __builtin_amdgcn_mfma_f32_16x16x32_f16(ah, w2r[kt][nt], acc[nt], 0, 0, 0);
        }

        // epilogue: ssp -> fp16 LDS transpose (stride 136) -> combine MFMA
        #pragma unroll
        for (int nt = 0; nt < 8; ++nt)
            #pragma unroll
            for (int reg = 0; reg < 4; ++reg)
                myH2[(quad * 4 + reg) * 136 + nt * 16 + m] =
                    (_Float16)ssp_f(acc[nt][reg] * INV_SQRT_H);

        f32x4 T0 = {0.f, 0.f, 0.f, 0.f};
        f32x4 T1 = {0.f, 0.f, 0.f, 0.f};
        #pragma unroll
        for (int kt = 0; kt < 4; ++kt) {
            half8 ah2 = *reinterpret_cast<const half8*>(&myH2[m * 136 + kt * 32 + quad * 8]);
            half8 bv = *reinterpret_cast<const half8*>(&sVf[(bl * 4 + kt) * 512 + lane * 8]);
            if (kt & 1) T1 = __builtin_amdgcn_mfma_f32_16x16x32_f16(ah2, bv, T1, 0, 0, 0);
            else        T0 = __builtin_amdgcn_mfma_f32_16x16x32_f16(ah2, bv, T0, 0, 0, 0);
        }

        // G-weight (T C-layout: col=lane&15=cm, row=quad*4+reg) + 16-lane reduce
        const int comp = (m >= 1 && m <= 8) ? (m - 1) : 0;
        float ps[4];
        #pragma unroll
        for (int reg = 0; reg < 4; ++reg) {
            const int row = quad * 4 + reg;
            const float Tv = T0[reg] + T1[reg];
            const float yv = sYw[wv][row][comp];
            const float g = (m == 0) ? 1.0f : ((m <= 8) ? yv : 0.0f);
            ps[reg] = Tv * g;
        }
        #pragma unroll
        for (int off = 1; off < 16; off <<= 1)
            #pragma unroll
            for (int reg = 0; reg < 4; ++reg)
                ps[reg] += __shfl_xor(ps[reg], off);
        #pragma unroll
        for (int reg = 0; reg < 4; ++reg) outAcc[reg] += ps[reg];
    }

    // ---- write partials (agent scope), then completion-counter protocol ----
    if (m == 0) {
        float* pb = partial + ((size_t)(z * 8 + bg)) * 64 + wv * 16 + quad * 4;
        #pragma unroll
        for (int reg = 0; reg < 4; ++reg)
            __hip_atomic_store(&pb[reg], outAcc[reg], __ATOMIC_RELAXED,
                               __HIP_MEMORY_SCOPE_AGENT);
    }
    __threadfence();
    __syncthreads();
    if (tid == 0) {
        unsigned old = atomicAdd(&counter[z], 1u);
        sLastFlag = (old == 0xAAAAAAAAu + 7u) ? 1u : 0u;
    }
    __syncthreads();
    if (sLastFlag) {
        __threadfence();
        if (tid < 64) {
            const float mk = mask[z * 64 + tid];
            float s = mk;
            #pragma unroll
            for (int off = 32; off > 0; off >>= 1) s += __shfl_xor(s, off);
            const float inv = rsqrtf(s);
            float acc = 0.f;
            #pragma unroll
            for (int b2 = 0; b2 < 8; ++b2)
                acc += __hip_atomic_load(&partial[((size_t)(z * 8 + b2)) * 64 + tid],
                                         __ATOMIC_RELAXED, __HIP_MEMORY_SCOPE_AGENT);
            out[z * 64 + tid] = sp_f(acc * inv) * mk;
        }
    }
}

extern "C" void kernel_launch(void* const* d_in, const int* in_sizes, int n_in,
                              void* d_out, int out_size, void* d_ws, size_t ws_size,
                              hipStream_t stream) {
    const float* rep  = (const float*)d_in[0];
    const float* geom = (const float*)d_in[1];
    const float* mask = (const float*)d_in[2];
    const float* W1   = (const float*)d_in[3];
    const float* W2   = (const float*)d_in[4];
    const float* W3   = (const float*)d_in[5];
    float* out = (float*)d_out;

    float* partial = (float*)d_ws;                           // 131072 B
    unsigned* counter = (unsigned*)((char*)d_ws + 131072);   // 64 uints (0xAA-poisoned)

    fused1<<<dim3(8, 64), 256, 0, stream>>>(rep, geom, mask, W1, W2, W3,
                                            partial, counter, out);
}